// Round 1
// baseline (935.293 us; speedup 1.0000x reference)
//
#include <hip/hip_runtime.h>

// ---------------------------------------------------------------------------
// GraphSAGE 2-layer forward, MI355X
//   layer: h = relu(mean_agg(x) @ W1l + b1 + x @ W1r)
//   out   =      mean_agg(h) @ W2l + b2 + h @ W2r
// Strategy: build CSR (by dst) once per call, gather-only SpMM (no f32
// atomics), W-resident-in-LDS fused vector GEMM.
// ---------------------------------------------------------------------------

// ---- edge layout detection (int64 vs int32 buffer) ------------------------
__global__ void detect_kernel(const int* __restrict__ e32, int nelem, int* flag) {
    __shared__ int bad;
    if (threadIdx.x == 0) bad = 0;
    __syncthreads();
    int half = nelem >> 1;  // = E
    int viol = 0;
    for (int i = threadIdx.x; i < 4096; i += blockDim.x) {
        long long k = ((long long)i * half) / 4096;   // k in [0, E)
        if (e32[2 * k + 1] != 0) viol++;              // int64 => hi words all 0
    }
    if (viol) atomicAdd(&bad, viol);
    __syncthreads();
    if (threadIdx.x == 0) flag[0] = (bad == 0) ? 1 : 0;   // 1 = int64 layout
}

// ---- decode edges to int32 src/dst + degree histogram ---------------------
__global__ void decode_deg_kernel(const int* __restrict__ e32, const int* __restrict__ flag,
                                  int* __restrict__ src, int* __restrict__ dst,
                                  int* __restrict__ deg, int E) {
    bool is64 = flag[0] != 0;
    int stride = gridDim.x * blockDim.x;
    for (int i = blockIdx.x * blockDim.x + threadIdx.x; i < E; i += stride) {
        int s, d;
        if (is64) { s = e32[2 * (long long)i]; d = e32[2 * ((long long)E + i)]; }
        else      { s = e32[i];                d = e32[E + i]; }
        src[i] = s; dst[i] = d;
        atomicAdd(&deg[d], 1);
    }
}

// ---- exclusive scan over deg (single block, wave-shuffle based) -----------
__global__ __launch_bounds__(1024) void scan_kernel(const int* __restrict__ deg,
                                                    int* __restrict__ off,
                                                    int* __restrict__ cursor, int N) {
    __shared__ int wsum[16];
    __shared__ int s_carry;
    int t = threadIdx.x;
    int lane = t & 63, w = t >> 6;
    if (t == 0) s_carry = 0;
    __syncthreads();
    for (int base = 0; base < N; base += 1024) {
        int i = base + t;
        int v = (i < N) ? deg[i] : 0;
        int sc = v;
        #pragma unroll
        for (int o = 1; o < 64; o <<= 1) {
            int u = __shfl_up(sc, o, 64);
            if (lane >= o) sc += u;
        }
        if (lane == 63) wsum[w] = sc;
        __syncthreads();
        int woff = 0;
        for (int j = 0; j < w; ++j) woff += wsum[j];
        int c = s_carry;
        int excl = c + woff + (sc - v);
        if (i < N) { off[i] = excl; cursor[i] = excl; }
        __syncthreads();
        if (t == 1023) s_carry = c + woff + sc;   // block total + carry
        __syncthreads();
    }
    if (t == 0) off[N] = s_carry;
}

// ---- bucket edges by dst --------------------------------------------------
__global__ void scatter_kernel(const int* __restrict__ src, const int* __restrict__ dst,
                               int* __restrict__ cursor, int* __restrict__ csr, int E) {
    int stride = gridDim.x * blockDim.x;
    for (int i = blockIdx.x * blockDim.x + threadIdx.x; i < E; i += stride) {
        int d = dst[i];
        int p = atomicAdd(&cursor[d], 1);
        csr[p] = src[i];
    }
}

// ---- SpMM: out[n] = mean of X rows listed in csr[off[n]..off[n+1]) --------
// one wave per node, 64 lanes x float2 = 128 features
__global__ __launch_bounds__(256) void spmm_mean_kernel(const float* __restrict__ X,
                                                        const int* __restrict__ off,
                                                        const int* __restrict__ csr,
                                                        float* __restrict__ out, int N) {
    int wid = blockIdx.x * (blockDim.x >> 6) + (threadIdx.x >> 6);
    int lane = threadIdx.x & 63;
    if (wid >= N) return;
    int b0 = off[wid], b1 = off[wid + 1];
    const float2* X2 = (const float2*)X;
    float ax = 0.f, ay = 0.f;
    int i = b0;
    for (; i + 3 < b1; i += 4) {
        int s0 = csr[i], s1 = csr[i + 1], s2 = csr[i + 2], s3 = csr[i + 3];
        float2 v0 = X2[s0 * 64 + lane];
        float2 v1 = X2[s1 * 64 + lane];
        float2 v2 = X2[s2 * 64 + lane];
        float2 v3 = X2[s3 * 64 + lane];
        ax += v0.x + v1.x + v2.x + v3.x;
        ay += v0.y + v1.y + v2.y + v3.y;
    }
    for (; i < b1; ++i) {
        int s = csr[i];
        float2 v = X2[s * 64 + lane];
        ax += v.x; ay += v.y;
    }
    int d = b1 - b0;
    float inv = (d > 0) ? 1.0f / (float)d : 0.0f;
    float2 m; m.x = ax * inv; m.y = ay * inv;
    ((float2*)out)[wid * 64 + lane] = m;
}

// ---- fused GEMM: out[r][c] = bias[c] + A1[r]@Wl[:,c] + A2[r]@Wr[:,c] ------
// W ([256][128] f32, 128KB) resident in LDS; 16 rows per tile; thread t:
// rows {t>>5, (t>>5)+8}, cols {4*(t&31)..+3}. Register prefetch of next A tile.
// Safe for out==A2 (block stages rows to LDS before writing its own rows).
__global__ __launch_bounds__(256) void gemm_kernel(const float* __restrict__ A1,
                                                   const float* __restrict__ A2,
                                                   const float* __restrict__ Wl,
                                                   const float* __restrict__ Wr,
                                                   const float* __restrict__ bias,
                                                   float* __restrict__ out,
                                                   int N, int doRelu) {
    extern __shared__ float lds[];
    float* ldsW = lds;              // [256][128]
    float* ldsA = lds + 256 * 128;  // [16][256]  (row: [0:128)=A1, [128:256)=A2)
    int t = threadIdx.x;

    // stage W (once per block)
    {
        const float4* Wl4 = (const float4*)Wl;
        const float4* Wr4 = (const float4*)Wr;
        float4* ldsW4 = (float4*)ldsW;
        #pragma unroll
        for (int i = 0; i < 32; ++i) {
            int idx = i * 256 + t;  // 0..8191 float4s
            ldsW4[idx] = (idx < 4096) ? Wl4[idx] : Wr4[idx - 4096];
        }
    }

    int cg = t & 31, rg = t >> 5;
    float4 bc = ((const float4*)bias)[cg];

    int ntiles = (N + 15) >> 4;
    float4 pre[4];

    auto prefetchA = [&](int tile) {
        long long row0 = (long long)tile * 16;
        #pragma unroll
        for (int j = 0; j < 4; ++j) {
            int q = j * 256 + t;          // 16B chunk id, 0..1023
            int r = q >> 6, c = q & 63;   // 64 chunks per row (256 floats)
            long long row = row0 + r;
            float4 v = make_float4(0.f, 0.f, 0.f, 0.f);
            if (row < N)
                v = (c < 32) ? ((const float4*)A1)[row * 32 + c]
                             : ((const float4*)A2)[row * 32 + (c - 32)];
            pre[j] = v;
        }
    };

    int tile = blockIdx.x;
    if (tile < ntiles) prefetchA(tile);
    for (; tile < ntiles; tile += gridDim.x) {
        __syncthreads();   // ldsA free
        #pragma unroll
        for (int j = 0; j < 4; ++j) ((float4*)ldsA)[j * 256 + t] = pre[j];
        __syncthreads();   // ldsA ready
        int nexttile = tile + gridDim.x;
        if (nexttile < ntiles) prefetchA(nexttile);

        const float* a0 = ldsA + rg * 256;
        const float* a1 = ldsA + (rg + 8) * 256;
        const float* wp = ldsW + cg * 4;
        float acc0[4] = {bc.x, bc.y, bc.z, bc.w};
        float acc1[4] = {bc.x, bc.y, bc.z, bc.w};
        for (int k = 0; k < 256; k += 4) {
            float4 a0v = *(const float4*)(a0 + k);
            float4 a1v = *(const float4*)(a1 + k);
            #pragma unroll
            for (int kk = 0; kk < 4; ++kk) {
                float4 wv = *(const float4*)(wp + (k + kk) * 128);
                float s0 = (&a0v.x)[kk];
                float s1 = (&a1v.x)[kk];
                acc0[0] += s0 * wv.x; acc0[1] += s0 * wv.y;
                acc0[2] += s0 * wv.z; acc0[3] += s0 * wv.w;
                acc1[0] += s1 * wv.x; acc1[1] += s1 * wv.y;
                acc1[2] += s1 * wv.z; acc1[3] += s1 * wv.w;
            }
        }
        if (doRelu) {
            #pragma unroll
            for (int j = 0; j < 4; ++j) {
                acc0[j] = fmaxf(acc0[j], 0.f);
                acc1[j] = fmaxf(acc1[j], 0.f);
            }
        }
        long long row0 = (long long)tile * 16;
        long long r0 = row0 + rg, r1 = row0 + rg + 8;
        if (r0 < N) ((float4*)out)[r0 * 32 + cg] = make_float4(acc0[0], acc0[1], acc0[2], acc0[3]);
        if (r1 < N) ((float4*)out)[r1 * 32 + cg] = make_float4(acc1[0], acc1[1], acc1[2], acc1[3]);
    }
}

// ---------------------------------------------------------------------------
extern "C" void kernel_launch(void* const* d_in, const int* in_sizes, int n_in,
                              void* d_out, int out_size, void* d_ws, size_t ws_size,
                              hipStream_t stream) {
    const float* x   = (const float*)d_in[0];
    const int*   eix = (const int*)d_in[1];
    const float* W1l = (const float*)d_in[2];
    const float* b1  = (const float*)d_in[3];
    const float* W1r = (const float*)d_in[4];
    const float* W2l = (const float*)d_in[5];
    const float* b2  = (const float*)d_in[6];
    const float* W2r = (const float*)d_in[7];
    float* out = (float*)d_out;

    int N = in_sizes[0] / 128;
    int E = in_sizes[1] / 2;
    if (N <= 0 || E <= 0) return;

    // workspace carve-out
    char* ws = (char*)d_ws;
    size_t o = 0;
    auto alloc = [&](size_t bytes) -> void* {
        o = (o + 255) & ~(size_t)255;
        void* p = ws + o;
        o += bytes;
        return p;
    };
    int*   flag   = (int*)alloc(4);
    int*   deg    = (int*)alloc((size_t)N * 4);
    int*   off    = (int*)alloc(((size_t)N + 1) * 4);
    int*   cursor = (int*)alloc((size_t)N * 4);
    int*   srcb   = (int*)alloc((size_t)E * 4);
    int*   dstb   = (int*)alloc((size_t)E * 4);
    int*   csr    = (int*)alloc((size_t)E * 4);
    float* mean   = (float*)alloc((size_t)N * 128 * 4);
    (void)ws_size;

    size_t gemm_lds = (size_t)(256 * 128 + 16 * 256) * sizeof(float);  // 144 KB
    static int attr_set = 0;
    (void)hipFuncSetAttribute((const void*)gemm_kernel,
                              hipFuncAttributeMaxDynamicSharedMemorySize,
                              (int)gemm_lds);
    (void)attr_set;

    hipMemsetAsync(deg, 0, (size_t)N * 4, stream);

    detect_kernel<<<1, 256, 0, stream>>>(eix, in_sizes[1], flag);
    decode_deg_kernel<<<1024, 256, 0, stream>>>(eix, flag, srcb, dstb, deg, E);
    scan_kernel<<<1, 1024, 0, stream>>>(deg, off, cursor, N);
    scatter_kernel<<<1024, 256, 0, stream>>>(srcb, dstb, cursor, csr, E);

    int spmm_grid = (N + 3) / 4;   // 4 waves (nodes) per 256-thread block

    // layer 1: mean1 = agg(x); h (-> d_out) = relu(mean1@W1l + b1 + x@W1r)
    spmm_mean_kernel<<<spmm_grid, 256, 0, stream>>>(x, off, csr, mean, N);
    gemm_kernel<<<256, 256, gemm_lds, stream>>>(mean, x, W1l, W1r, b1, out, N, 1);

    // layer 2: mean2 = agg(h); out = mean2@W2l + b2 + h@W2r (in-place safe)
    spmm_mean_kernel<<<spmm_grid, 256, 0, stream>>>(out, off, csr, mean, N);
    gemm_kernel<<<256, 256, gemm_lds, stream>>>(mean, out, W2l, W2r, b2, out, N, 0);
}

// Round 3
// 533.921 us; speedup vs baseline: 1.7517x; 1.7517x over previous
//
#include <hip/hip_runtime.h>

// ---------------------------------------------------------------------------
// GraphSAGE 2-layer forward, MI355X (gfx950)
//   h   = relu(mean_agg(x) @ W1l + b1 + x @ W1r)
//   out =      mean_agg(h) @ W2l + b2 + h @ W2r
// R3: fix R2's A-panel staging (full 128-feature rows; was staging half ->
// uninitialized LDS -> NaN). MFMA bf16 GEMM, bf16 gather SpMM, CSR build.
// ---------------------------------------------------------------------------

typedef __attribute__((ext_vector_type(8))) short short8;
typedef __attribute__((ext_vector_type(4))) float floatx4;
typedef __attribute__((ext_vector_type(4))) unsigned short ushort4v;

__device__ inline unsigned short f2b(float f) {  // f32 -> bf16 (RNE)
    unsigned u = __builtin_bit_cast(unsigned, f);
    return (unsigned short)((u + 0x7FFFu + ((u >> 16) & 1u)) >> 16);
}
__device__ inline float blo(unsigned v) { return __builtin_bit_cast(float, v << 16); }
__device__ inline float bhi(unsigned v) { return __builtin_bit_cast(float, v & 0xffff0000u); }

// ---- edge layout detection (int64 vs int32 buffer) ------------------------
__global__ void detect_kernel(const int* __restrict__ e32, int nelem, int* flag) {
    __shared__ int bad;
    if (threadIdx.x == 0) bad = 0;
    __syncthreads();
    int half = nelem >> 1;  // = E
    int viol = 0;
    for (int i = threadIdx.x; i < 4096; i += blockDim.x) {
        long long k = ((long long)i * half) / 4096;
        if (e32[2 * k + 1] != 0) viol++;   // int64 => hi words all 0
    }
    if (viol) atomicAdd(&bad, viol);
    __syncthreads();
    if (threadIdx.x == 0) flag[0] = (bad == 0) ? 1 : 0;  // 1 = int64 layout
}

__device__ inline void decode_edge(const int* e32, bool is64, int E, int i, int& s, int& d) {
    if (is64) { s = e32[2 * (long long)i]; d = e32[2 * ((long long)E + i)]; }
    else      { s = e32[i];                d = e32[E + i]; }
}

// ---- degree histogram -----------------------------------------------------
__global__ void deg_kernel(const int* __restrict__ e32, const int* __restrict__ flag,
                           int* __restrict__ deg, int E) {
    bool is64 = flag[0] != 0;
    int stride = gridDim.x * blockDim.x;
    for (int i = blockIdx.x * blockDim.x + threadIdx.x; i < E; i += stride) {
        int s, d; decode_edge(e32, is64, E, i, s, d);
        atomicAdd(&deg[d], 1);
    }
}

// ---- exclusive scan over deg (single block) -------------------------------
__global__ __launch_bounds__(1024) void scan_kernel(const int* __restrict__ deg,
                                                    int* __restrict__ off,
                                                    int* __restrict__ cursor, int N) {
    __shared__ int wsum[16];
    __shared__ int s_carry;
    int t = threadIdx.x;
    int lane = t & 63, w = t >> 6;
    if (t == 0) s_carry = 0;
    __syncthreads();
    for (int base = 0; base < N; base += 1024) {
        int i = base + t;
        int v = (i < N) ? deg[i] : 0;
        int sc = v;
        #pragma unroll
        for (int o = 1; o < 64; o <<= 1) {
            int u = __shfl_up(sc, o, 64);
            if (lane >= o) sc += u;
        }
        if (lane == 63) wsum[w] = sc;
        __syncthreads();
        int woff = 0;
        for (int j = 0; j < w; ++j) woff += wsum[j];
        int c = s_carry;
        int excl = c + woff + (sc - v);
        if (i < N) { off[i] = excl; cursor[i] = excl; }
        __syncthreads();
        if (t == 1023) s_carry = c + woff + sc;
        __syncthreads();
    }
    if (t == 0) off[N] = s_carry;
}

// ---- bucket edges by dst --------------------------------------------------
__global__ void scatter_kernel(const int* __restrict__ e32, const int* __restrict__ flag,
                               int* __restrict__ cursor, int* __restrict__ csr, int E) {
    bool is64 = flag[0] != 0;
    int stride = gridDim.x * blockDim.x;
    for (int i = blockIdx.x * blockDim.x + threadIdx.x; i < E; i += stride) {
        int s, d; decode_edge(e32, is64, E, i, s, d);
        int p = atomicAdd(&cursor[d], 1);
        csr[p] = s;
    }
}

// ---- f32 -> bf16 table ----------------------------------------------------
__global__ void cvt_kernel(const float* __restrict__ in, unsigned short* __restrict__ out, int n4) {
    int stride = gridDim.x * blockDim.x;
    for (int i = blockIdx.x * blockDim.x + threadIdx.x; i < n4; i += stride) {
        float4 v = ((const float4*)in)[i];
        ushort4v o;
        o[0] = f2b(v.x); o[1] = f2b(v.y); o[2] = f2b(v.z); o[3] = f2b(v.w);
        ((ushort4v*)out)[i] = o;
    }
}

// ---- SpMM mean: gather rows of X (bf16 or f32), write bf16 mean -----------
// one wave per node; 64 lanes x 2 features
template<int BF16IN>
__global__ __launch_bounds__(256) void spmm_mean_kernel(const void* __restrict__ Xv,
                                                        const int* __restrict__ off,
                                                        const int* __restrict__ csr,
                                                        unsigned* __restrict__ outb, int N) {
    int wid = blockIdx.x * 4 + (threadIdx.x >> 6);
    int lane = threadIdx.x & 63;
    if (wid >= N) return;
    int b0 = off[wid], b1 = off[wid + 1];
    float ax = 0.f, ay = 0.f;
    int i = b0;
    if (BF16IN) {
        const unsigned* X = (const unsigned*)Xv;   // row = 64 uints (128 bf16)
        for (; i + 3 < b1; i += 4) {
            int s0 = csr[i], s1 = csr[i + 1], s2 = csr[i + 2], s3 = csr[i + 3];
            unsigned v0 = X[(long long)s0 * 64 + lane];
            unsigned v1 = X[(long long)s1 * 64 + lane];
            unsigned v2 = X[(long long)s2 * 64 + lane];
            unsigned v3 = X[(long long)s3 * 64 + lane];
            ax += blo(v0) + blo(v1) + blo(v2) + blo(v3);
            ay += bhi(v0) + bhi(v1) + bhi(v2) + bhi(v3);
        }
        for (; i < b1; ++i) {
            unsigned v = X[(long long)csr[i] * 64 + lane];
            ax += blo(v); ay += bhi(v);
        }
    } else {
        const float2* X = (const float2*)Xv;
        for (; i + 3 < b1; i += 4) {
            int s0 = csr[i], s1 = csr[i + 1], s2 = csr[i + 2], s3 = csr[i + 3];
            float2 v0 = X[(long long)s0 * 64 + lane];
            float2 v1 = X[(long long)s1 * 64 + lane];
            float2 v2 = X[(long long)s2 * 64 + lane];
            float2 v3 = X[(long long)s3 * 64 + lane];
            ax += v0.x + v1.x + v2.x + v3.x;
            ay += v0.y + v1.y + v2.y + v3.y;
        }
        for (; i < b1; ++i) {
            float2 v = X[(long long)csr[i] * 64 + lane];
            ax += v.x; ay += v.y;
        }
    }
    int dgr = b1 - b0;
    float inv = (dgr > 0) ? 1.0f / (float)dgr : 0.0f;
    unsigned pack = (unsigned)f2b(ax * inv) | ((unsigned)f2b(ay * inv) << 16);
    outb[(long long)wid * 64 + lane] = pack;
}

// ---- MFMA GEMM: Out[r][c] = bias[c] + Am[r]@W[0:128] + Ax[r]@W[128:256] ---
// A panels bf16 in LDS (padded row stride 136), Wt [n=128][k=256] bf16 in LDS
// (padded stride 264). 64 rows/tile, 4 waves x 32 cols each, double-buffered.
// XF32: Ax is f32 (else bf16). OUTMODE: 0=f32+relu, 1=bf16+relu, 2=f32.
#define WT_SZ   (128 * 264)          // shorts
#define APANEL  (64 * 136)           // shorts
#define ABUF    (2 * APANEL)         // M panel + X panel
#define GEMM_LDS ((WT_SZ + 2 * ABUF) * 2)   // bytes = 137216

template<int XF32, int OUTMODE>
__global__ __launch_bounds__(256, 1) void gemm_mfma_kernel(
    const unsigned short* __restrict__ Am, const void* __restrict__ Ax,
    const float* __restrict__ Wl, const float* __restrict__ Wr,
    const float* __restrict__ bias, void* __restrict__ Out,
    int N, int ntiles)
{
    extern __shared__ unsigned short lds[];
    unsigned short* Wt = lds;
    int t = threadIdx.x;
    int lane = t & 63, wv = t >> 6;
    int lm = lane & 15, q = lane >> 4;
    int c0 = wv * 32;

    // stage Wt[n][k] = (k<128 ? Wl : Wr)[k%128][n], bf16, padded stride 264
    for (int it = 0; it < 64; ++it) {
        int n = t & 127;
        int kp = it * 2 + (t >> 7);           // 0..127
        int k = 2 * kp;
        const float* Wsrc = (k < 128) ? (Wl + k * 128) : (Wr + (k - 128) * 128);
        unsigned pack = (unsigned)f2b(Wsrc[n]) | ((unsigned)f2b(Wsrc[128 + n]) << 16);
        *(unsigned*)(Wt + n * 264 + k) = pack;
    }

    float bias0 = bias[c0 + lm];
    float bias1 = bias[c0 + 16 + lm];

    // one 64-row tile = 64 rows x 128 feats = 1024 short8 chunks per panel;
    // 256 threads x j=0..3 : cid = row*16 + cp  (16 chunks per row)
    short8 pm[4], px[4];
    auto prefetch = [&](int tl) {
        long long row0 = (long long)tl * 64;
        #pragma unroll
        for (int j = 0; j < 4; ++j) {
            int cid = j * 256 + t;
            int row = cid >> 4, cp = cid & 15;
            long long gr = row0 + row;
            bool ok = gr < (long long)N;
            pm[j] = ok ? *(const short8*)(Am + gr * 128 + cp * 8) : (short8)0;
            if (XF32) {
                short8 s = (short8)0;
                if (ok) {
                    const float* xp = (const float*)Ax + gr * 128 + cp * 8;
                    floatx4 u0 = *(const floatx4*)xp;
                    floatx4 u1 = *(const floatx4*)(xp + 4);
                    s[0] = (short)f2b(u0[0]); s[1] = (short)f2b(u0[1]);
                    s[2] = (short)f2b(u0[2]); s[3] = (short)f2b(u0[3]);
                    s[4] = (short)f2b(u1[0]); s[5] = (short)f2b(u1[1]);
                    s[6] = (short)f2b(u1[2]); s[7] = (short)f2b(u1[3]);
                }
                px[j] = s;
            } else {
                px[j] = ok ? *(const short8*)((const unsigned short*)Ax + gr * 128 + cp * 8)
                           : (short8)0;
            }
        }
    };

    int tile = blockIdx.x;
    if (tile < ntiles) prefetch(tile);
    int buf = 0;
    for (; tile < ntiles; tile += gridDim.x) {
        unsigned short* A = lds + WT_SZ + buf * ABUF;
        __syncthreads();   // prior reads of this buffer done (also Wt ready, iter 0)
        #pragma unroll
        for (int j = 0; j < 4; ++j) {
            int cid = j * 256 + t;
            int row = cid >> 4, cp = cid & 15;
            *(short8*)(A + row * 136 + cp * 8) = pm[j];
            *(short8*)(A + APANEL + row * 136 + cp * 8) = px[j];
        }
        __syncthreads();   // tile staged
        int nt = tile + gridDim.x;
        if (nt < ntiles) prefetch(nt);

        floatx4 acc[4][2];
        #pragma unroll
        for (int rf = 0; rf < 4; ++rf) {
            acc[rf][0] = (floatx4)bias0;
            acc[rf][1] = (floatx4)bias1;
        }
        #pragma unroll
        for (int ks = 0; ks < 8; ++ks) {
            const unsigned short* P = A + (ks >= 4 ? APANEL : 0);
            int k0 = (ks & 3) * 32 + q * 8;
            short8 b0 = *(const short8*)(Wt + (c0 + lm) * 264 + ks * 32 + q * 8);
            short8 b1 = *(const short8*)(Wt + (c0 + 16 + lm) * 264 + ks * 32 + q * 8);
            #pragma unroll
            for (int rf = 0; rf < 4; ++rf) {
                short8 a = *(const short8*)(P + (rf * 16 + lm) * 136 + k0);
                acc[rf][0] = __builtin_amdgcn_mfma_f32_16x16x32_bf16(a, b0, acc[rf][0], 0, 0, 0);
                acc[rf][1] = __builtin_amdgcn_mfma_f32_16x16x32_bf16(a, b1, acc[rf][1], 0, 0, 0);
            }
        }

        long long r0 = (long long)tile * 64;
        #pragma unroll
        for (int rf = 0; rf < 4; ++rf) {
            #pragma unroll
            for (int cf = 0; cf < 2; ++cf) {
                int col = c0 + cf * 16 + lm;
                #pragma unroll
                for (int rg = 0; rg < 4; ++rg) {
                    long long rr = r0 + rf * 16 + q * 4 + rg;
                    if (rr < (long long)N) {
                        float v = acc[rf][cf][rg];
                        if (OUTMODE != 2) v = fmaxf(v, 0.f);
                        if (OUTMODE == 1)
                            ((unsigned short*)Out)[rr * 128 + col] = f2b(v);
                        else
                            ((float*)Out)[rr * 128 + col] = v;
                    }
                }
            }
        }
        buf ^= 1;
    }
}

// ---------------------------------------------------------------------------
extern "C" void kernel_launch(void* const* d_in, const int* in_sizes, int n_in,
                              void* d_out, int out_size, void* d_ws, size_t ws_size,
                              hipStream_t stream) {
    const float* x   = (const float*)d_in[0];
    const int*   eix = (const int*)d_in[1];
    const float* W1l = (const float*)d_in[2];
    const float* b1  = (const float*)d_in[3];
    const float* W1r = (const float*)d_in[4];
    const float* W2l = (const float*)d_in[5];
    const float* b2  = (const float*)d_in[6];
    const float* W2r = (const float*)d_in[7];
    float* out = (float*)d_out;

    int N = in_sizes[0] / 128;
    int E = in_sizes[1] / 2;
    if (N <= 0 || E <= 0) return;

    char* ws = (char*)d_ws;
    size_t o = 0;
    auto alloc = [&](size_t bytes) -> void* {
        o = (o + 255) & ~(size_t)255;
        void* p = ws + o;
        o += bytes;
        return p;
    };
    int*            flag   = (int*)alloc(4);
    int*            deg    = (int*)alloc((size_t)N * 4);
    int*            off    = (int*)alloc(((size_t)N + 1) * 4);
    int*            cursor = (int*)alloc((size_t)N * 4);
    int*            csr    = (int*)alloc((size_t)E * 4);
    unsigned short* xb     = (unsigned short*)alloc((size_t)N * 128 * 2);
    unsigned short* meanb  = (unsigned short*)alloc((size_t)N * 128 * 2);
    unsigned short* hb     = (unsigned short*)alloc((size_t)N * 128 * 2);
    bool full = (o <= ws_size);   // room for bf16 h?

    (void)hipFuncSetAttribute((const void*)gemm_mfma_kernel<0, 0>,
                              hipFuncAttributeMaxDynamicSharedMemorySize, GEMM_LDS);
    (void)hipFuncSetAttribute((const void*)gemm_mfma_kernel<0, 1>,
                              hipFuncAttributeMaxDynamicSharedMemorySize, GEMM_LDS);
    (void)hipFuncSetAttribute((const void*)gemm_mfma_kernel<0, 2>,
                              hipFuncAttributeMaxDynamicSharedMemorySize, GEMM_LDS);
    (void)hipFuncSetAttribute((const void*)gemm_mfma_kernel<1, 2>,
                              hipFuncAttributeMaxDynamicSharedMemorySize, GEMM_LDS);

    hipMemsetAsync(deg, 0, (size_t)N * 4, stream);

    // CSR build
    detect_kernel<<<1, 256, 0, stream>>>(eix, in_sizes[1], flag);
    deg_kernel<<<1024, 256, 0, stream>>>(eix, flag, deg, E);
    scan_kernel<<<1, 1024, 0, stream>>>(deg, off, cursor, N);
    scatter_kernel<<<1024, 256, 0, stream>>>(eix, flag, cursor, csr, E);

    // x -> bf16
    cvt_kernel<<<2048, 256, 0, stream>>>(x, xb, N * 32);

    int spmm_grid = (N + 3) / 4;
    int ntiles = (N + 63) / 64;
    int ggrid = ntiles < 256 ? ntiles : 256;

    // layer 1
    spmm_mean_kernel<1><<<spmm_grid, 256, 0, stream>>>(xb, off, csr, (unsigned*)meanb, N);
    if (full) {
        gemm_mfma_kernel<0, 1><<<ggrid, 256, GEMM_LDS, stream>>>(
            meanb, xb, W1l, W1r, b1, hb, N, ntiles);
        // layer 2 (h bf16)
        spmm_mean_kernel<1><<<spmm_grid, 256, 0, stream>>>(hb, off, csr, (unsigned*)meanb, N);
        gemm_mfma_kernel<0, 2><<<ggrid, 256, GEMM_LDS, stream>>>(
            meanb, hb, W2l, W2r, b2, out, N, ntiles);
    } else {
        gemm_mfma_kernel<0, 0><<<ggrid, 256, GEMM_LDS, stream>>>(
            meanb, xb, W1l, W1r, b1, out, N, ntiles);
        // layer 2 (h f32 in d_out; in-place safe: each block reads only rows it owns)
        spmm_mean_kernel<0><<<spmm_grid, 256, 0, stream>>>(out, off, csr, (unsigned*)meanb, N);
        gemm_mfma_kernel<1, 2><<<ggrid, 256, GEMM_LDS, stream>>>(
            meanb, out, W2l, W2r, b2, out, N, ntiles);
    }
}

// Round 4
// 396.837 us; speedup vs baseline: 2.3569x; 1.3454x over previous
//
#include <hip/hip_runtime.h>

// ---------------------------------------------------------------------------
// GraphSAGE 2-layer forward, MI355X (gfx950)
//   h   = relu(mean_agg(x) @ W1l + b1 + x @ W1r)
//   out =      mean_agg(h) @ W2l + b2 + h @ W2r
// R4: replace random-write CSR scatter (106MB HBM write-amp) with bucketed
// two-pass counting sort (32-node buckets, cache-resident within-bucket
// scatter). MFMA bf16 GEMM + bf16 gather SpMM unchanged from R3.
// ---------------------------------------------------------------------------

typedef __attribute__((ext_vector_type(8))) short short8;
typedef __attribute__((ext_vector_type(4))) float floatx4;
typedef __attribute__((ext_vector_type(4))) unsigned short ushort4v;

#define BSH 5                      // bucket = 32 consecutive dst nodes

__device__ inline unsigned short f2b(float f) {  // f32 -> bf16 (RNE)
    unsigned u = __builtin_bit_cast(unsigned, f);
    return (unsigned short)((u + 0x7FFFu + ((u >> 16) & 1u)) >> 16);
}
__device__ inline float blo(unsigned v) { return __builtin_bit_cast(float, v << 16); }
__device__ inline float bhi(unsigned v) { return __builtin_bit_cast(float, v & 0xffff0000u); }

// ---- edge layout detection (int64 vs int32 buffer) ------------------------
__global__ void detect_kernel(const int* __restrict__ e32, int nelem, int* flag) {
    __shared__ int bad;
    if (threadIdx.x == 0) bad = 0;
    __syncthreads();
    int half = nelem >> 1;  // = E
    int viol = 0;
    for (int i = threadIdx.x; i < 4096; i += blockDim.x) {
        long long k = ((long long)i * half) / 4096;
        if (e32[2 * k + 1] != 0) viol++;   // int64 => hi words all 0
    }
    if (viol) atomicAdd(&bad, viol);
    __syncthreads();
    if (threadIdx.x == 0) flag[0] = (bad == 0) ? 1 : 0;  // 1 = int64 layout
}

__device__ inline void decode_edge(const int* e32, bool is64, int E, int i, int& s, int& d) {
    if (is64) { s = e32[2 * (long long)i]; d = e32[2 * ((long long)E + i)]; }
    else      { s = e32[i];                d = e32[E + i]; }
}

// ---- bucket count: LDS histogram per block, coalesced flush ---------------
__global__ __launch_bounds__(256) void bucket_count_kernel(const int* __restrict__ e32,
                                                           const int* __restrict__ flag,
                                                           int* __restrict__ bcnt,
                                                           int E, int nb) {
    extern __shared__ int lh[];
    for (int i = threadIdx.x; i < nb; i += blockDim.x) lh[i] = 0;
    __syncthreads();
    bool is64 = flag[0] != 0;
    int stride = gridDim.x * blockDim.x;
    for (int i = blockIdx.x * blockDim.x + threadIdx.x; i < E; i += stride) {
        int d = is64 ? e32[2 * ((long long)E + i)] : e32[E + i];
        atomicAdd(&lh[d >> BSH], 1);
    }
    __syncthreads();
    for (int i = threadIdx.x; i < nb; i += blockDim.x) {
        int c = lh[i];
        if (c) atomicAdd(&bcnt[i], c);
    }
}
// fallback when nb too large for LDS
__global__ void bucket_count_global_kernel(const int* __restrict__ e32,
                                           const int* __restrict__ flag,
                                           int* __restrict__ bcnt, int E) {
    bool is64 = flag[0] != 0;
    int stride = gridDim.x * blockDim.x;
    for (int i = blockIdx.x * blockDim.x + threadIdx.x; i < E; i += stride) {
        int d = is64 ? e32[2 * ((long long)E + i)] : e32[E + i];
        atomicAdd(&bcnt[d >> BSH], 1);
    }
}

// ---- exclusive scan (single block) ----------------------------------------
__global__ __launch_bounds__(1024) void scan_kernel(const int* __restrict__ deg,
                                                    int* __restrict__ off,
                                                    int* __restrict__ cursor, int N) {
    __shared__ int wsum[16];
    __shared__ int s_carry;
    int t = threadIdx.x;
    int lane = t & 63, w = t >> 6;
    if (t == 0) s_carry = 0;
    __syncthreads();
    for (int base = 0; base < N; base += 1024) {
        int i = base + t;
        int v = (i < N) ? deg[i] : 0;
        int sc = v;
        #pragma unroll
        for (int o = 1; o < 64; o <<= 1) {
            int u = __shfl_up(sc, o, 64);
            if (lane >= o) sc += u;
        }
        if (lane == 63) wsum[w] = sc;
        __syncthreads();
        int woff = 0;
        for (int j = 0; j < w; ++j) woff += wsum[j];
        int c = s_carry;
        int excl = c + woff + (sc - v);
        if (i < N) { off[i] = excl; cursor[i] = excl; }
        __syncthreads();
        if (t == 1023) s_carry = c + woff + sc;
        __syncthreads();
    }
    if (t == 0) off[N] = s_carry;
}

// ---- scatter edges into bucket regions (append; frontier stays hot) -------
__global__ void bucket_scatter_kernel(const int* __restrict__ e32,
                                      const int* __restrict__ flag,
                                      int* __restrict__ bcur,
                                      int2* __restrict__ pairs, int E) {
    bool is64 = flag[0] != 0;
    int stride = gridDim.x * blockDim.x;
    for (int i = blockIdx.x * blockDim.x + threadIdx.x; i < E; i += stride) {
        int s, d; decode_edge(e32, is64, E, i, s, d);
        int p = atomicAdd(&bcur[d >> BSH], 1);
        pairs[p] = make_int2(s, d);
    }
}

// ---- per-bucket local CSR build: LDS hist + scan + cache-resident scatter -
__global__ __launch_bounds__(256) void csr_build_kernel(const int2* __restrict__ pairs,
                                                        const int* __restrict__ boff,
                                                        int* __restrict__ off,
                                                        int* __restrict__ csr,
                                                        int N, int nb, int E) {
    __shared__ int ldeg[32], loff[32], lcur[32];
    int b = blockIdx.x;
    if (b >= nb) return;
    int t = threadIdx.x;
    int p0 = boff[b], p1 = boff[b + 1];
    int base = b << BSH;
    if (t < 32) ldeg[t] = 0;
    __syncthreads();
    for (int i = p0 + t; i < p1; i += 256) atomicAdd(&ldeg[pairs[i].y & 31], 1);
    __syncthreads();
    if (t < 32) {
        int v = ldeg[t];
        int sc = v;
        #pragma unroll
        for (int o = 1; o < 32; o <<= 1) {
            int u = __shfl_up(sc, o, 64);
            if (t >= o) sc += u;
        }
        loff[t] = sc - v;
        lcur[t] = sc - v;
        int d = base + t;
        if (d < N) off[d] = p0 + sc - v;
    }
    __syncthreads();
    for (int i = p0 + t; i < p1; i += 256) {
        int2 e = pairs[i];
        int p = atomicAdd(&lcur[e.y & 31], 1);
        csr[p0 + p] = e.x;
    }
    if (b == 0 && t == 0) off[N] = E;
}

// ---- f32 -> bf16 table ----------------------------------------------------
__global__ void cvt_kernel(const float* __restrict__ in, unsigned short* __restrict__ out, int n4) {
    int stride = gridDim.x * blockDim.x;
    for (int i = blockIdx.x * blockDim.x + threadIdx.x; i < n4; i += stride) {
        float4 v = ((const float4*)in)[i];
        ushort4v o;
        o[0] = f2b(v.x); o[1] = f2b(v.y); o[2] = f2b(v.z); o[3] = f2b(v.w);
        ((ushort4v*)out)[i] = o;
    }
}

// ---- SpMM mean: gather rows of X (bf16 or f32), write bf16 mean -----------
template<int BF16IN>
__global__ __launch_bounds__(256) void spmm_mean_kernel(const void* __restrict__ Xv,
                                                        const int* __restrict__ off,
                                                        const int* __restrict__ csr,
                                                        unsigned* __restrict__ outb, int N) {
    int wid = blockIdx.x * 4 + (threadIdx.x >> 6);
    int lane = threadIdx.x & 63;
    if (wid >= N) return;
    int b0 = off[wid], b1 = off[wid + 1];
    float ax = 0.f, ay = 0.f;
    int i = b0;
    if (BF16IN) {
        const unsigned* X = (const unsigned*)Xv;   // row = 64 uints (128 bf16)
        for (; i + 3 < b1; i += 4) {
            int s0 = csr[i], s1 = csr[i + 1], s2 = csr[i + 2], s3 = csr[i + 3];
            unsigned v0 = X[(long long)s0 * 64 + lane];
            unsigned v1 = X[(long long)s1 * 64 + lane];
            unsigned v2 = X[(long long)s2 * 64 + lane];
            unsigned v3 = X[(long long)s3 * 64 + lane];
            ax += blo(v0) + blo(v1) + blo(v2) + blo(v3);
            ay += bhi(v0) + bhi(v1) + bhi(v2) + bhi(v3);
        }
        for (; i < b1; ++i) {
            unsigned v = X[(long long)csr[i] * 64 + lane];
            ax += blo(v); ay += bhi(v);
        }
    } else {
        const float2* X = (const float2*)Xv;
        for (; i + 3 < b1; i += 4) {
            int s0 = csr[i], s1 = csr[i + 1], s2 = csr[i + 2], s3 = csr[i + 3];
            float2 v0 = X[(long long)s0 * 64 + lane];
            float2 v1 = X[(long long)s1 * 64 + lane];
            float2 v2 = X[(long long)s2 * 64 + lane];
            float2 v3 = X[(long long)s3 * 64 + lane];
            ax += v0.x + v1.x + v2.x + v3.x;
            ay += v0.y + v1.y + v2.y + v3.y;
        }
        for (; i < b1; ++i) {
            float2 v = X[(long long)csr[i] * 64 + lane];
            ax += v.x; ay += v.y;
        }
    }
    int dgr = b1 - b0;
    float inv = (dgr > 0) ? 1.0f / (float)dgr : 0.0f;
    unsigned pack = (unsigned)f2b(ax * inv) | ((unsigned)f2b(ay * inv) << 16);
    outb[(long long)wid * 64 + lane] = pack;
}

// ---- MFMA GEMM: Out[r][c] = bias[c] + Am[r]@W[0:128] + Ax[r]@W[128:256] ---
#define WT_SZ   (128 * 264)          // shorts
#define APANEL  (64 * 136)           // shorts
#define ABUF    (2 * APANEL)
#define GEMM_LDS ((WT_SZ + 2 * ABUF) * 2)   // bytes = 137216

template<int XF32, int OUTMODE>
__global__ __launch_bounds__(256, 1) void gemm_mfma_kernel(
    const unsigned short* __restrict__ Am, const void* __restrict__ Ax,
    const float* __restrict__ Wl, const float* __restrict__ Wr,
    const float* __restrict__ bias, void* __restrict__ Out,
    int N, int ntiles)
{
    extern __shared__ unsigned short lds[];
    unsigned short* Wt = lds;
    int t = threadIdx.x;
    int lane = t & 63, wv = t >> 6;
    int lm = lane & 15, q = lane >> 4;
    int c0 = wv * 32;

    for (int it = 0; it < 64; ++it) {
        int n = t & 127;
        int kp = it * 2 + (t >> 7);
        int k = 2 * kp;
        const float* Wsrc = (k < 128) ? (Wl + k * 128) : (Wr + (k - 128) * 128);
        unsigned pack = (unsigned)f2b(Wsrc[n]) | ((unsigned)f2b(Wsrc[128 + n]) << 16);
        *(unsigned*)(Wt + n * 264 + k) = pack;
    }

    float bias0 = bias[c0 + lm];
    float bias1 = bias[c0 + 16 + lm];

    short8 pm[4], px[4];
    auto prefetch = [&](int tl) {
        long long row0 = (long long)tl * 64;
        #pragma unroll
        for (int j = 0; j < 4; ++j) {
            int cid = j * 256 + t;
            int row = cid >> 4, cp = cid & 15;
            long long gr = row0 + row;
            bool ok = gr < (long long)N;
            pm[j] = ok ? *(const short8*)(Am + gr * 128 + cp * 8) : (short8)0;
            if (XF32) {
                short8 s = (short8)0;
                if (ok) {
                    const float* xp = (const float*)Ax + gr * 128 + cp * 8;
                    floatx4 u0 = *(const floatx4*)xp;
                    floatx4 u1 = *(const floatx4*)(xp + 4);
                    s[0] = (short)f2b(u0[0]); s[1] = (short)f2b(u0[1]);
                    s[2] = (short)f2b(u0[2]); s[3] = (short)f2b(u0[3]);
                    s[4] = (short)f2b(u1[0]); s[5] = (short)f2b(u1[1]);
                    s[6] = (short)f2b(u1[2]); s[7] = (short)f2b(u1[3]);
                }
                px[j] = s;
            } else {
                px[j] = ok ? *(const short8*)((const unsigned short*)Ax + gr * 128 + cp * 8)
                           : (short8)0;
            }
        }
    };

    int tile = blockIdx.x;
    if (tile < ntiles) prefetch(tile);
    int buf = 0;
    for (; tile < ntiles; tile += gridDim.x) {
        unsigned short* A = lds + WT_SZ + buf * ABUF;
        __syncthreads();
        #pragma unroll
        for (int j = 0; j < 4; ++j) {
            int cid = j * 256 + t;
            int row = cid >> 4, cp = cid & 15;
            *(short8*)(A + row * 136 + cp * 8) = pm[j];
            *(short8*)(A + APANEL + row * 136 + cp * 8) = px[j];
        }
        __syncthreads();
        int nt = tile + gridDim.x;
        if (nt < ntiles) prefetch(nt);

        floatx4 acc[4][2];
        #pragma unroll
        for (int rf = 0; rf < 4; ++rf) {
            acc[rf][0] = (floatx4)bias0;
            acc[rf][1] = (floatx4)bias1;
        }
        #pragma unroll
        for (int ks = 0; ks < 8; ++ks) {
            const unsigned short* P = A + (ks >= 4 ? APANEL : 0);
            int k0 = (ks & 3) * 32 + q * 8;
            short8 b0 = *(const short8*)(Wt + (c0 + lm) * 264 + ks * 32 + q * 8);
            short8 b1 = *(const short8*)(Wt + (c0 + 16 + lm) * 264 + ks * 32 + q * 8);
            #pragma unroll
            for (int rf = 0; rf < 4; ++rf) {
                short8 a = *(const short8*)(P + (rf * 16 + lm) * 136 + k0);
                acc[rf][0] = __builtin_amdgcn_mfma_f32_16x16x32_bf16(a, b0, acc[rf][0], 0, 0, 0);
                acc[rf][1] = __builtin_amdgcn_mfma_f32_16x16x32_bf16(a, b1, acc[rf][1], 0, 0, 0);
            }
        }

        long long r0 = (long long)tile * 64;
        #pragma unroll
        for (int rf = 0; rf < 4; ++rf) {
            #pragma unroll
            for (int cf = 0; cf < 2; ++cf) {
                int col = c0 + cf * 16 + lm;
                #pragma unroll
                for (int rg = 0; rg < 4; ++rg) {
                    long long rr = r0 + rf * 16 + q * 4 + rg;
                    if (rr < (long long)N) {
                        float v = acc[rf][cf][rg];
                        if (OUTMODE != 2) v = fmaxf(v, 0.f);
                        if (OUTMODE == 1)
                            ((unsigned short*)Out)[rr * 128 + col] = f2b(v);
                        else
                            ((float*)Out)[rr * 128 + col] = v;
                    }
                }
            }
        }
        buf ^= 1;
    }
}

// ---------------------------------------------------------------------------
extern "C" void kernel_launch(void* const* d_in, const int* in_sizes, int n_in,
                              void* d_out, int out_size, void* d_ws, size_t ws_size,
                              hipStream_t stream) {
    const float* x   = (const float*)d_in[0];
    const int*   eix = (const int*)d_in[1];
    const float* W1l = (const float*)d_in[2];
    const float* b1  = (const float*)d_in[3];
    const float* W1r = (const float*)d_in[4];
    const float* W2l = (const float*)d_in[5];
    const float* b2  = (const float*)d_in[6];
    const float* W2r = (const float*)d_in[7];
    float* out = (float*)d_out;

    int N = in_sizes[0] / 128;
    int E = in_sizes[1] / 2;
    if (N <= 0 || E <= 0) return;
    int nb = (N + 31) >> BSH;

    char* ws = (char*)d_ws;
    size_t o = 0;
    auto alloc = [&](size_t bytes) -> void* {
        o = (o + 255) & ~(size_t)255;
        void* p = ws + o;
        o += bytes;
        return p;
    };
    int*            flag   = (int*)alloc(4);
    int*            bcnt   = (int*)alloc((size_t)nb * 4);
    int*            boff   = (int*)alloc(((size_t)nb + 1) * 4);
    int*            bcur   = (int*)alloc((size_t)nb * 4);
    int*            off    = (int*)alloc(((size_t)N + 1) * 4);
    int*            csr    = (int*)alloc((size_t)E * 4);
    unsigned short* xb     = (unsigned short*)alloc((size_t)N * 128 * 2);
    unsigned short* meanb  = (unsigned short*)alloc((size_t)N * 128 * 2);
    unsigned short* hb     = (unsigned short*)alloc((size_t)N * 128 * 2);
    bool full = (o <= ws_size);   // room for bf16 h?
    // pairs aliases meanb: dead before spmm writes meanb, needs E*8 <= N*256B
    int2* pairs = (int2*)meanb;

    (void)hipFuncSetAttribute((const void*)gemm_mfma_kernel<0, 0>,
                              hipFuncAttributeMaxDynamicSharedMemorySize, GEMM_LDS);
    (void)hipFuncSetAttribute((const void*)gemm_mfma_kernel<0, 1>,
                              hipFuncAttributeMaxDynamicSharedMemorySize, GEMM_LDS);
    (void)hipFuncSetAttribute((const void*)gemm_mfma_kernel<0, 2>,
                              hipFuncAttributeMaxDynamicSharedMemorySize, GEMM_LDS);
    (void)hipFuncSetAttribute((const void*)gemm_mfma_kernel<1, 2>,
                              hipFuncAttributeMaxDynamicSharedMemorySize, GEMM_LDS);

    hipMemsetAsync(bcnt, 0, (size_t)nb * 4, stream);

    // CSR build (bucketed counting sort)
    detect_kernel<<<1, 256, 0, stream>>>(eix, in_sizes[1], flag);
    size_t cnt_lds = (size_t)nb * 4;
    if (cnt_lds <= 48 * 1024) {
        bucket_count_kernel<<<128, 256, cnt_lds, stream>>>(eix, flag, bcnt, E, nb);
    } else {
        bucket_count_global_kernel<<<1024, 256, 0, stream>>>(eix, flag, bcnt, E);
    }
    scan_kernel<<<1, 1024, 0, stream>>>(bcnt, boff, bcur, nb);
    bucket_scatter_kernel<<<1024, 256, 0, stream>>>(eix, flag, bcur, pairs, E);
    csr_build_kernel<<<nb, 256, 0, stream>>>(pairs, boff, off, csr, N, nb, E);

    // x -> bf16
    cvt_kernel<<<2048, 256, 0, stream>>>(x, xb, N * 32);

    int spmm_grid = (N + 3) / 4;
    int ntiles = (N + 63) / 64;
    int ggrid = ntiles < 256 ? ntiles : 256;

    // layer 1
    spmm_mean_kernel<1><<<spmm_grid, 256, 0, stream>>>(xb, off, csr, (unsigned*)meanb, N);
    if (full) {
        gemm_mfma_kernel<0, 1><<<ggrid, 256, GEMM_LDS, stream>>>(
            meanb, xb, W1l, W1r, b1, hb, N, ntiles);
        spmm_mean_kernel<1><<<spmm_grid, 256, 0, stream>>>(hb, off, csr, (unsigned*)meanb, N);
        gemm_mfma_kernel<0, 2><<<ggrid, 256, GEMM_LDS, stream>>>(
            meanb, hb, W2l, W2r, b2, out, N, ntiles);
    } else {
        gemm_mfma_kernel<0, 0><<<ggrid, 256, GEMM_LDS, stream>>>(
            meanb, xb, W1l, W1r, b1, out, N, ntiles);
        spmm_mean_kernel<0><<<spmm_grid, 256, 0, stream>>>(out, off, csr, (unsigned*)meanb, N);
        gemm_mfma_kernel<1, 2><<<ggrid, 256, GEMM_LDS, stream>>>(
            meanb, out, W2l, W2r, b2, out, N, ntiles);
    }
}

// Round 5
// 287.416 us; speedup vs baseline: 3.2541x; 1.3807x over previous
//
#include <hip/hip_runtime.h>

// ---------------------------------------------------------------------------
// GraphSAGE 2-layer forward, MI355X (gfx950)
//   h   = relu(mean_agg(x) @ W1l + b1 + x @ W1r)
//   out =      mean_agg(h) @ W2l + b2 + h @ W2r
// R5: CSR build via two-level binning sort with chunk-private reservations
// (kills the 88MB write-amp + 1.6M hot atomics of R4's bucket_scatter).
// MFMA bf16 GEMM + bf16 gather SpMM unchanged from R3/R4.
// ---------------------------------------------------------------------------

typedef __attribute__((ext_vector_type(8))) short short8;
typedef __attribute__((ext_vector_type(4))) float floatx4;
typedef __attribute__((ext_vector_type(4))) unsigned short ushort4v;

#define BSH1 9                     // coarse bucket = 512 consecutive dst nodes
#define CHUNK 8192                 // edges per chunk (coarse scatter)

__device__ inline unsigned short f2b(float f) {  // f32 -> bf16 (RNE)
    unsigned u = __builtin_bit_cast(unsigned, f);
    return (unsigned short)((u + 0x7FFFu + ((u >> 16) & 1u)) >> 16);
}
__device__ inline float blo(unsigned v) { return __builtin_bit_cast(float, v << 16); }
__device__ inline float bhi(unsigned v) { return __builtin_bit_cast(float, v & 0xffff0000u); }

// ---- edge layout detection (int64 vs int32 buffer) ------------------------
__global__ void detect_kernel(const int* __restrict__ e32, int nelem, int* flag) {
    __shared__ int bad;
    if (threadIdx.x == 0) bad = 0;
    __syncthreads();
    int half = nelem >> 1;  // = E
    int viol = 0;
    for (int i = threadIdx.x; i < 4096; i += blockDim.x) {
        long long k = ((long long)i * half) / 4096;
        if (e32[2 * k + 1] != 0) viol++;   // int64 => hi words all 0
    }
    if (viol) atomicAdd(&bad, viol);
    __syncthreads();
    if (threadIdx.x == 0) flag[0] = (bad == 0) ? 1 : 0;  // 1 = int64 layout
}

__device__ inline void decode_edge(const int* e32, bool is64, int E, int i, int& s, int& d) {
    if (is64) { s = e32[2 * (long long)i]; d = e32[2 * ((long long)E + i)]; }
    else      { s = e32[i];                d = e32[E + i]; }
}

// ---- coarse bucket count: LDS histogram per block, tiny global flush ------
__global__ __launch_bounds__(256) void coarse_count_kernel(const int* __restrict__ e32,
                                                           const int* __restrict__ flag,
                                                           int* __restrict__ bcnt,
                                                           int E, int nb1) {
    extern __shared__ int lh[];
    for (int i = threadIdx.x; i < nb1; i += blockDim.x) lh[i] = 0;
    __syncthreads();
    bool is64 = flag[0] != 0;
    int stride = gridDim.x * blockDim.x;
    for (int i = blockIdx.x * blockDim.x + threadIdx.x; i < E; i += stride) {
        int d = is64 ? e32[2 * ((long long)E + i)] : e32[E + i];
        atomicAdd(&lh[d >> BSH1], 1);
    }
    __syncthreads();
    for (int i = threadIdx.x; i < nb1; i += blockDim.x) {
        int c = lh[i];
        if (c) atomicAdd(&bcnt[i], c);
    }
}

// ---- exclusive scan (single block) ----------------------------------------
__global__ __launch_bounds__(1024) void scan_kernel(const int* __restrict__ deg,
                                                    int* __restrict__ off,
                                                    int* __restrict__ cursor, int N) {
    __shared__ int wsum[16];
    __shared__ int s_carry;
    int t = threadIdx.x;
    int lane = t & 63, w = t >> 6;
    if (t == 0) s_carry = 0;
    __syncthreads();
    for (int base = 0; base < N; base += 1024) {
        int i = base + t;
        int v = (i < N) ? deg[i] : 0;
        int sc = v;
        #pragma unroll
        for (int o = 1; o < 64; o <<= 1) {
            int u = __shfl_up(sc, o, 64);
            if (lane >= o) sc += u;
        }
        if (lane == 63) wsum[w] = sc;
        __syncthreads();
        int woff = 0;
        for (int j = 0; j < w; ++j) woff += wsum[j];
        int c = s_carry;
        int excl = c + woff + (sc - v);
        if (i < N) { off[i] = excl; cursor[i] = excl; }
        __syncthreads();
        if (t == 1023) s_carry = c + woff + sc;
        __syncthreads();
    }
    if (t == 0) off[N] = s_carry;
}

// ---- coarse scatter: per-chunk LDS hist -> one reservation per bucket -----
// writes land in chunk-private contiguous runs (~336B) => no line bouncing
__global__ __launch_bounds__(256) void coarse_scatter_kernel(const int* __restrict__ e32,
                                                             const int* __restrict__ flag,
                                                             int* __restrict__ bcur,
                                                             int2* __restrict__ pairs,
                                                             int E, int nb1) {
    extern __shared__ int lh[];            // [nb1] cursor/hist + [nb1] base
    int t = threadIdx.x;
    bool is64 = flag[0] != 0;
    int nchunks = (E + CHUNK - 1) / CHUNK;
    for (int ch = blockIdx.x; ch < nchunks; ch += gridDim.x) {
        int e0 = ch * CHUNK;
        int e1 = min(e0 + CHUNK, E);
        for (int i = t; i < nb1; i += 256) lh[i] = 0;
        __syncthreads();
        for (int i = e0 + t; i < e1; i += 256) {
            int d = is64 ? e32[2 * ((long long)E + i)] : e32[E + i];
            atomicAdd(&lh[d >> BSH1], 1);
        }
        __syncthreads();
        for (int i = t; i < nb1; i += 256) {
            int c = lh[i];
            lh[nb1 + i] = c ? atomicAdd(&bcur[i], c) : 0;   // global reservation
            lh[i] = 0;                                      // reuse as local cursor
        }
        __syncthreads();
        for (int i = e0 + t; i < e1; i += 256) {
            int s, d; decode_edge(e32, is64, E, i, s, d);
            int k = d >> BSH1;
            int r = atomicAdd(&lh[k], 1);
            pairs[lh[nb1 + k] + r] = make_int2(s, d);
        }
        __syncthreads();
    }
}

// ---- fine CSR build: one block per coarse bucket (region L2-resident) -----
__global__ __launch_bounds__(256) void fine_csr_kernel(const int2* __restrict__ pairs,
                                                       const int* __restrict__ boff,
                                                       int* __restrict__ off,
                                                       int* __restrict__ csr,
                                                       int N, int nb1, int E) {
    __shared__ int ldeg[512], loff[512];
    __shared__ int wsum[4];
    int b = blockIdx.x;
    if (b >= nb1) return;
    int t = threadIdx.x;
    int p0 = boff[b], p1 = boff[b + 1];
    int base = b << BSH1;
    ldeg[2 * t] = 0; ldeg[2 * t + 1] = 0;
    __syncthreads();
    for (int i = p0 + t; i < p1; i += 256) atomicAdd(&ldeg[pairs[i].y & 511], 1);
    __syncthreads();
    // exclusive scan of 512 entries with 256 threads (pairs per thread)
    {
        int lane = t & 63, w = t >> 6;
        int v0 = ldeg[2 * t], v1 = ldeg[2 * t + 1];
        int v = v0 + v1, sc = v;
        #pragma unroll
        for (int o = 1; o < 64; o <<= 1) {
            int u = __shfl_up(sc, o, 64);
            if (lane >= o) sc += u;
        }
        if (lane == 63) wsum[w] = sc;
        __syncthreads();
        int cross = 0;
        for (int j = 0; j < w; ++j) cross += wsum[j];
        int ex = cross + sc - v;
        loff[2 * t] = ex;
        loff[2 * t + 1] = ex + v0;
        int d0 = base + 2 * t, d1 = d0 + 1;
        if (d0 < N) off[d0] = p0 + ex;
        if (d1 < N) off[d1] = p0 + ex + v0;
    }
    __syncthreads();
    ldeg[2 * t] = 0; ldeg[2 * t + 1] = 0;   // reuse as cursors
    __syncthreads();
    for (int i = p0 + t; i < p1; i += 256) {
        int2 e = pairs[i];
        int dl = e.y & 511;
        int r = atomicAdd(&ldeg[dl], 1);
        csr[p0 + loff[dl] + r] = e.x;
    }
    if (b == 0 && t == 0) off[N] = E;
}

// ---- f32 -> bf16 table ----------------------------------------------------
__global__ void cvt_kernel(const float* __restrict__ in, unsigned short* __restrict__ out, int n4) {
    int stride = gridDim.x * blockDim.x;
    for (int i = blockIdx.x * blockDim.x + threadIdx.x; i < n4; i += stride) {
        float4 v = ((const float4*)in)[i];
        ushort4v o;
        o[0] = f2b(v.x); o[1] = f2b(v.y); o[2] = f2b(v.z); o[3] = f2b(v.w);
        ((ushort4v*)out)[i] = o;
    }
}

// ---- SpMM mean: gather rows of X (bf16 or f32), write bf16 mean -----------
template<int BF16IN>
__global__ __launch_bounds__(256) void spmm_mean_kernel(const void* __restrict__ Xv,
                                                        const int* __restrict__ off,
                                                        const int* __restrict__ csr,
                                                        unsigned* __restrict__ outb, int N) {
    int wid = blockIdx.x * 4 + (threadIdx.x >> 6);
    int lane = threadIdx.x & 63;
    if (wid >= N) return;
    int b0 = off[wid], b1 = off[wid + 1];
    float ax = 0.f, ay = 0.f;
    int i = b0;
    if (BF16IN) {
        const unsigned* X = (const unsigned*)Xv;   // row = 64 uints (128 bf16)
        for (; i + 3 < b1; i += 4) {
            int s0 = csr[i], s1 = csr[i + 1], s2 = csr[i + 2], s3 = csr[i + 3];
            unsigned v0 = X[(long long)s0 * 64 + lane];
            unsigned v1 = X[(long long)s1 * 64 + lane];
            unsigned v2 = X[(long long)s2 * 64 + lane];
            unsigned v3 = X[(long long)s3 * 64 + lane];
            ax += blo(v0) + blo(v1) + blo(v2) + blo(v3);
            ay += bhi(v0) + bhi(v1) + bhi(v2) + bhi(v3);
        }
        for (; i < b1; ++i) {
            unsigned v = X[(long long)csr[i] * 64 + lane];
            ax += blo(v); ay += bhi(v);
        }
    } else {
        const float2* X = (const float2*)Xv;
        for (; i + 3 < b1; i += 4) {
            int s0 = csr[i], s1 = csr[i + 1], s2 = csr[i + 2], s3 = csr[i + 3];
            float2 v0 = X[(long long)s0 * 64 + lane];
            float2 v1 = X[(long long)s1 * 64 + lane];
            float2 v2 = X[(long long)s2 * 64 + lane];
            float2 v3 = X[(long long)s3 * 64 + lane];
            ax += v0.x + v1.x + v2.x + v3.x;
            ay += v0.y + v1.y + v2.y + v3.y;
        }
        for (; i < b1; ++i) {
            float2 v = X[(long long)csr[i] * 64 + lane];
            ax += v.x; ay += v.y;
        }
    }
    int dgr = b1 - b0;
    float inv = (dgr > 0) ? 1.0f / (float)dgr : 0.0f;
    unsigned pack = (unsigned)f2b(ax * inv) | ((unsigned)f2b(ay * inv) << 16);
    outb[(long long)wid * 64 + lane] = pack;
}

// ---- MFMA GEMM: Out[r][c] = bias[c] + Am[r]@W[0:128] + Ax[r]@W[128:256] ---
#define WT_SZ   (128 * 264)          // shorts
#define APANEL  (64 * 136)           // shorts
#define ABUF    (2 * APANEL)
#define GEMM_LDS ((WT_SZ + 2 * ABUF) * 2)   // bytes = 137216

template<int XF32, int OUTMODE>
__global__ __launch_bounds__(256, 1) void gemm_mfma_kernel(
    const unsigned short* __restrict__ Am, const void* __restrict__ Ax,
    const float* __restrict__ Wl, const float* __restrict__ Wr,
    const float* __restrict__ bias, void* __restrict__ Out,
    int N, int ntiles)
{
    extern __shared__ unsigned short lds[];
    unsigned short* Wt = lds;
    int t = threadIdx.x;
    int lane = t & 63, wv = t >> 6;
    int lm = lane & 15, q = lane >> 4;
    int c0 = wv * 32;

    for (int it = 0; it < 64; ++it) {
        int n = t & 127;
        int kp = it * 2 + (t >> 7);
        int k = 2 * kp;
        const float* Wsrc = (k < 128) ? (Wl + k * 128) : (Wr + (k - 128) * 128);
        unsigned pack = (unsigned)f2b(Wsrc[n]) | ((unsigned)f2b(Wsrc[128 + n]) << 16);
        *(unsigned*)(Wt + n * 264 + k) = pack;
    }

    float bias0 = bias[c0 + lm];
    float bias1 = bias[c0 + 16 + lm];

    short8 pm[4], px[4];
    auto prefetch = [&](int tl) {
        long long row0 = (long long)tl * 64;
        #pragma unroll
        for (int j = 0; j < 4; ++j) {
            int cid = j * 256 + t;
            int row = cid >> 4, cp = cid & 15;
            long long gr = row0 + row;
            bool ok = gr < (long long)N;
            pm[j] = ok ? *(const short8*)(Am + gr * 128 + cp * 8) : (short8)0;
            if (XF32) {
                short8 s = (short8)0;
                if (ok) {
                    const float* xp = (const float*)Ax + gr * 128 + cp * 8;
                    floatx4 u0 = *(const floatx4*)xp;
                    floatx4 u1 = *(const floatx4*)(xp + 4);
                    s[0] = (short)f2b(u0[0]); s[1] = (short)f2b(u0[1]);
                    s[2] = (short)f2b(u0[2]); s[3] = (short)f2b(u0[3]);
                    s[4] = (short)f2b(u1[0]); s[5] = (short)f2b(u1[1]);
                    s[6] = (short)f2b(u1[2]); s[7] = (short)f2b(u1[3]);
                }
                px[j] = s;
            } else {
                px[j] = ok ? *(const short8*)((const unsigned short*)Ax + gr * 128 + cp * 8)
                           : (short8)0;
            }
        }
    };

    int tile = blockIdx.x;
    if (tile < ntiles) prefetch(tile);
    int buf = 0;
    for (; tile < ntiles; tile += gridDim.x) {
        unsigned short* A = lds + WT_SZ + buf * ABUF;
        __syncthreads();
        #pragma unroll
        for (int j = 0; j < 4; ++j) {
            int cid = j * 256 + t;
            int row = cid >> 4, cp = cid & 15;
            *(short8*)(A + row * 136 + cp * 8) = pm[j];
            *(short8*)(A + APANEL + row * 136 + cp * 8) = px[j];
        }
        __syncthreads();
        int nt = tile + gridDim.x;
        if (nt < ntiles) prefetch(nt);

        floatx4 acc[4][2];
        #pragma unroll
        for (int rf = 0; rf < 4; ++rf) {
            acc[rf][0] = (floatx4)bias0;
            acc[rf][1] = (floatx4)bias1;
        }
        #pragma unroll
        for (int ks = 0; ks < 8; ++ks) {
            const unsigned short* P = A + (ks >= 4 ? APANEL : 0);
            int k0 = (ks & 3) * 32 + q * 8;
            short8 b0 = *(const short8*)(Wt + (c0 + lm) * 264 + ks * 32 + q * 8);
            short8 b1 = *(const short8*)(Wt + (c0 + 16 + lm) * 264 + ks * 32 + q * 8);
            #pragma unroll
            for (int rf = 0; rf < 4; ++rf) {
                short8 a = *(const short8*)(P + (rf * 16 + lm) * 136 + k0);
                acc[rf][0] = __builtin_amdgcn_mfma_f32_16x16x32_bf16(a, b0, acc[rf][0], 0, 0, 0);
                acc[rf][1] = __builtin_amdgcn_mfma_f32_16x16x32_bf16(a, b1, acc[rf][1], 0, 0, 0);
            }
        }

        long long r0 = (long long)tile * 64;
        #pragma unroll
        for (int rf = 0; rf < 4; ++rf) {
            #pragma unroll
            for (int cf = 0; cf < 2; ++cf) {
                int col = c0 + cf * 16 + lm;
                #pragma unroll
                for (int rg = 0; rg < 4; ++rg) {
                    long long rr = r0 + rf * 16 + q * 4 + rg;
                    if (rr < (long long)N) {
                        float v = acc[rf][cf][rg];
                        if (OUTMODE != 2) v = fmaxf(v, 0.f);
                        if (OUTMODE == 1)
                            ((unsigned short*)Out)[rr * 128 + col] = f2b(v);
                        else
                            ((float*)Out)[rr * 128 + col] = v;
                    }
                }
            }
        }
        buf ^= 1;
    }
}

// ---------------------------------------------------------------------------
extern "C" void kernel_launch(void* const* d_in, const int* in_sizes, int n_in,
                              void* d_out, int out_size, void* d_ws, size_t ws_size,
                              hipStream_t stream) {
    const float* x   = (const float*)d_in[0];
    const int*   eix = (const int*)d_in[1];
    const float* W1l = (const float*)d_in[2];
    const float* b1  = (const float*)d_in[3];
    const float* W1r = (const float*)d_in[4];
    const float* W2l = (const float*)d_in[5];
    const float* b2  = (const float*)d_in[6];
    const float* W2r = (const float*)d_in[7];
    float* out = (float*)d_out;

    int N = in_sizes[0] / 128;
    int E = in_sizes[1] / 2;
    if (N <= 0 || E <= 0) return;
    int nb1 = (N + (1 << BSH1) - 1) >> BSH1;

    char* ws = (char*)d_ws;
    size_t o = 0;
    auto alloc = [&](size_t bytes) -> void* {
        o = (o + 255) & ~(size_t)255;
        void* p = ws + o;
        o += bytes;
        return p;
    };
    int*            flag   = (int*)alloc(4);
    int*            bcnt   = (int*)alloc((size_t)nb1 * 4);
    int*            boff   = (int*)alloc(((size_t)nb1 + 1) * 4);
    int*            bcur   = (int*)alloc((size_t)nb1 * 4);
    int*            off    = (int*)alloc(((size_t)N + 1) * 4);
    int*            csr    = (int*)alloc((size_t)E * 4);
    unsigned short* xb     = (unsigned short*)alloc((size_t)N * 128 * 2);
    unsigned short* meanb  = (unsigned short*)alloc((size_t)N * 128 * 2);
    unsigned short* hb     = (unsigned short*)alloc((size_t)N * 128 * 2);
    bool full = (o <= ws_size);   // room for bf16 h?
    // pairs aliases meanb: dead before spmm writes meanb (needs E*8 <= N*256B)
    int2* pairs = (int2*)meanb;

    (void)hipFuncSetAttribute((const void*)gemm_mfma_kernel<0, 0>,
                              hipFuncAttributeMaxDynamicSharedMemorySize, GEMM_LDS);
    (void)hipFuncSetAttribute((const void*)gemm_mfma_kernel<0, 1>,
                              hipFuncAttributeMaxDynamicSharedMemorySize, GEMM_LDS);
    (void)hipFuncSetAttribute((const void*)gemm_mfma_kernel<0, 2>,
                              hipFuncAttributeMaxDynamicSharedMemorySize, GEMM_LDS);
    (void)hipFuncSetAttribute((const void*)gemm_mfma_kernel<1, 2>,
                              hipFuncAttributeMaxDynamicSharedMemorySize, GEMM_LDS);

    hipMemsetAsync(bcnt, 0, (size_t)nb1 * 4, stream);

    // CSR build: coarse count -> scan -> chunk-private scatter -> fine sort
    detect_kernel<<<1, 256, 0, stream>>>(eix, in_sizes[1], flag);
    size_t cnt_lds = (size_t)nb1 * 4;
    coarse_count_kernel<<<256, 256, cnt_lds, stream>>>(eix, flag, bcnt, E, nb1);
    scan_kernel<<<1, 1024, 0, stream>>>(bcnt, boff, bcur, nb1);
    int nchunks = (E + CHUNK - 1) / CHUNK;
    int sgrid = nchunks < 2048 ? nchunks : 2048;
    coarse_scatter_kernel<<<sgrid, 256, 2 * cnt_lds, stream>>>(eix, flag, bcur, pairs, E, nb1);
    fine_csr_kernel<<<nb1, 256, 0, stream>>>(pairs, boff, off, csr, N, nb1, E);

    // x -> bf16
    cvt_kernel<<<2048, 256, 0, stream>>>(x, xb, N * 32);

    int spmm_grid = (N + 3) / 4;
    int ntiles = (N + 63) / 64;
    int ggrid = ntiles < 256 ? ntiles : 256;

    // layer 1
    spmm_mean_kernel<1><<<spmm_grid, 256, 0, stream>>>(xb, off, csr, (unsigned*)meanb, N);
    if (full) {
        gemm_mfma_kernel<0, 1><<<ggrid, 256, GEMM_LDS, stream>>>(
            meanb, xb, W1l, W1r, b1, hb, N, ntiles);
        spmm_mean_kernel<1><<<spmm_grid, 256, 0, stream>>>(hb, off, csr, (unsigned*)meanb, N);
        gemm_mfma_kernel<0, 2><<<ggrid, 256, GEMM_LDS, stream>>>(
            meanb, hb, W2l, W2r, b2, out, N, ntiles);
    } else {
        gemm_mfma_kernel<0, 0><<<ggrid, 256, GEMM_LDS, stream>>>(
            meanb, xb, W1l, W1r, b1, out, N, ntiles);
        spmm_mean_kernel<0><<<spmm_grid, 256, 0, stream>>>(out, off, csr, (unsigned*)meanb, N);
        gemm_mfma_kernel<1, 2><<<ggrid, 256, GEMM_LDS, stream>>>(
            meanb, out, W2l, W2r, b2, out, N, ntiles);
    }
}

// Round 6
// 258.936 us; speedup vs baseline: 3.6121x; 1.1100x over previous
//
#include <hip/hip_runtime.h>

// ---------------------------------------------------------------------------
// GraphSAGE 2-layer forward, MI355X (gfx950)
//   h   = relu(mean_agg(x) @ W1l + b1 + x @ W1r)
//   out =      mean_agg(h) @ W2l + b2 + h @ W2r
// R6: spmm gather unroll x8 (MLP), packed (src|dstlocal) pairs (halve sort
// traffic), GEMM 512-thread blocks (8 waves/CU). CSR two-level sort from R5.
// ---------------------------------------------------------------------------

typedef __attribute__((ext_vector_type(8))) short short8;
typedef __attribute__((ext_vector_type(4))) float floatx4;
typedef __attribute__((ext_vector_type(4))) unsigned short ushort4v;

#define BSH1 9                     // coarse bucket = 512 consecutive dst nodes
#define CHUNK 8192                 // edges per chunk (coarse scatter)
// packed pair: src in bits[0:23), dst&511 in bits[23:32). requires N < 2^23

__device__ inline unsigned short f2b(float f) {  // f32 -> bf16 (RNE)
    unsigned u = __builtin_bit_cast(unsigned, f);
    return (unsigned short)((u + 0x7FFFu + ((u >> 16) & 1u)) >> 16);
}
__device__ inline float blo(unsigned v) { return __builtin_bit_cast(float, v << 16); }
__device__ inline float bhi(unsigned v) { return __builtin_bit_cast(float, v & 0xffff0000u); }

// ---- edge layout detection (int64 vs int32 buffer) ------------------------
__global__ void detect_kernel(const int* __restrict__ e32, int nelem, int* flag) {
    __shared__ int bad;
    if (threadIdx.x == 0) bad = 0;
    __syncthreads();
    int half = nelem >> 1;  // = E
    int viol = 0;
    for (int i = threadIdx.x; i < 4096; i += blockDim.x) {
        long long k = ((long long)i * half) / 4096;
        if (e32[2 * k + 1] != 0) viol++;   // int64 => hi words all 0
    }
    if (viol) atomicAdd(&bad, viol);
    __syncthreads();
    if (threadIdx.x == 0) flag[0] = (bad == 0) ? 1 : 0;  // 1 = int64 layout
}

__device__ inline void decode_edge(const int* e32, bool is64, int E, int i, int& s, int& d) {
    if (is64) { s = e32[2 * (long long)i]; d = e32[2 * ((long long)E + i)]; }
    else      { s = e32[i];                d = e32[E + i]; }
}

// ---- coarse bucket count: LDS histogram per block, tiny global flush ------
__global__ __launch_bounds__(256) void coarse_count_kernel(const int* __restrict__ e32,
                                                           const int* __restrict__ flag,
                                                           int* __restrict__ bcnt,
                                                           int E, int nb1) {
    extern __shared__ int lh[];
    for (int i = threadIdx.x; i < nb1; i += blockDim.x) lh[i] = 0;
    __syncthreads();
    bool is64 = flag[0] != 0;
    int stride = gridDim.x * blockDim.x;
    for (int i = blockIdx.x * blockDim.x + threadIdx.x; i < E; i += stride) {
        int d = is64 ? e32[2 * ((long long)E + i)] : e32[E + i];
        atomicAdd(&lh[d >> BSH1], 1);
    }
    __syncthreads();
    for (int i = threadIdx.x; i < nb1; i += blockDim.x) {
        int c = lh[i];
        if (c) atomicAdd(&bcnt[i], c);
    }
}

// ---- exclusive scan (single block) ----------------------------------------
__global__ __launch_bounds__(1024) void scan_kernel(const int* __restrict__ deg,
                                                    int* __restrict__ off,
                                                    int* __restrict__ cursor, int N) {
    __shared__ int wsum[16];
    __shared__ int s_carry;
    int t = threadIdx.x;
    int lane = t & 63, w = t >> 6;
    if (t == 0) s_carry = 0;
    __syncthreads();
    for (int base = 0; base < N; base += 1024) {
        int i = base + t;
        int v = (i < N) ? deg[i] : 0;
        int sc = v;
        #pragma unroll
        for (int o = 1; o < 64; o <<= 1) {
            int u = __shfl_up(sc, o, 64);
            if (lane >= o) sc += u;
        }
        if (lane == 63) wsum[w] = sc;
        __syncthreads();
        int woff = 0;
        for (int j = 0; j < w; ++j) woff += wsum[j];
        int c = s_carry;
        int excl = c + woff + (sc - v);
        if (i < N) { off[i] = excl; cursor[i] = excl; }
        __syncthreads();
        if (t == 1023) s_carry = c + woff + sc;
        __syncthreads();
    }
    if (t == 0) off[N] = s_carry;
}

// ---- coarse scatter: per-chunk LDS hist -> one reservation per bucket -----
// writes packed (src|dlocal) into chunk-private contiguous runs
__global__ __launch_bounds__(256) void coarse_scatter_kernel(const int* __restrict__ e32,
                                                             const int* __restrict__ flag,
                                                             int* __restrict__ bcur,
                                                             unsigned* __restrict__ pairs,
                                                             int E, int nb1) {
    extern __shared__ int lh[];            // [nb1] cursor/hist + [nb1] base
    int t = threadIdx.x;
    bool is64 = flag[0] != 0;
    int nchunks = (E + CHUNK - 1) / CHUNK;
    for (int ch = blockIdx.x; ch < nchunks; ch += gridDim.x) {
        int e0 = ch * CHUNK;
        int e1 = min(e0 + CHUNK, E);
        for (int i = t; i < nb1; i += 256) lh[i] = 0;
        __syncthreads();
        for (int i = e0 + t; i < e1; i += 256) {
            int d = is64 ? e32[2 * ((long long)E + i)] : e32[E + i];
            atomicAdd(&lh[d >> BSH1], 1);
        }
        __syncthreads();
        for (int i = t; i < nb1; i += 256) {
            int c = lh[i];
            lh[nb1 + i] = c ? atomicAdd(&bcur[i], c) : 0;   // global reservation
            lh[i] = 0;                                      // reuse as local cursor
        }
        __syncthreads();
        for (int i = e0 + t; i < e1; i += 256) {
            int s, d; decode_edge(e32, is64, E, i, s, d);
            int k = d >> BSH1;
            int r = atomicAdd(&lh[k], 1);
            pairs[lh[nb1 + k] + r] = (unsigned)s | ((unsigned)(d & ((1 << BSH1) - 1)) << 23);
        }
        __syncthreads();
    }
}

// ---- fine CSR build: one block per coarse bucket (region L2-resident) -----
__global__ __launch_bounds__(256) void fine_csr_kernel(const unsigned* __restrict__ pairs,
                                                       const int* __restrict__ boff,
                                                       int* __restrict__ off,
                                                       int* __restrict__ csr,
                                                       int N, int nb1, int E) {
    __shared__ int ldeg[512], loff[512];
    __shared__ int wsum[4];
    int b = blockIdx.x;
    if (b >= nb1) return;
    int t = threadIdx.x;
    int p0 = boff[b], p1 = boff[b + 1];
    int base = b << BSH1;
    ldeg[2 * t] = 0; ldeg[2 * t + 1] = 0;
    __syncthreads();
    for (int i = p0 + t; i < p1; i += 256) atomicAdd(&ldeg[pairs[i] >> 23], 1);
    __syncthreads();
    // exclusive scan of 512 entries with 256 threads
    {
        int lane = t & 63, w = t >> 6;
        int v0 = ldeg[2 * t], v1 = ldeg[2 * t + 1];
        int v = v0 + v1, sc = v;
        #pragma unroll
        for (int o = 1; o < 64; o <<= 1) {
            int u = __shfl_up(sc, o, 64);
            if (lane >= o) sc += u;
        }
        if (lane == 63) wsum[w] = sc;
        __syncthreads();
        int cross = 0;
        for (int j = 0; j < w; ++j) cross += wsum[j];
        int ex = cross + sc - v;
        loff[2 * t] = ex;
        loff[2 * t + 1] = ex + v0;
        int d0 = base + 2 * t, d1 = d0 + 1;
        if (d0 < N) off[d0] = p0 + ex;
        if (d1 < N) off[d1] = p0 + ex + v0;
    }
    __syncthreads();
    ldeg[2 * t] = 0; ldeg[2 * t + 1] = 0;   // reuse as cursors
    __syncthreads();
    for (int i = p0 + t; i < p1; i += 256) {
        unsigned e = pairs[i];
        int dl = e >> 23;
        int r = atomicAdd(&ldeg[dl], 1);
        csr[p0 + loff[dl] + r] = (int)(e & 0x7FFFFFu);
    }
    if (b == 0 && t == 0) off[N] = E;
}

// ---- f32 -> bf16 table ----------------------------------------------------
__global__ void cvt_kernel(const float* __restrict__ in, unsigned short* __restrict__ out, int n4) {
    int stride = gridDim.x * blockDim.x;
    for (int i = blockIdx.x * blockDim.x + threadIdx.x; i < n4; i += stride) {
        float4 v = ((const float4*)in)[i];
        ushort4v o;
        o[0] = f2b(v.x); o[1] = f2b(v.y); o[2] = f2b(v.z); o[3] = f2b(v.w);
        ((ushort4v*)out)[i] = o;
    }
}

// ---- SpMM mean: gather rows of X (bf16 or f32), write bf16 mean -----------
// one wave per node; unroll 8 for memory-level parallelism
template<int BF16IN>
__global__ __launch_bounds__(256) void spmm_mean_kernel(const void* __restrict__ Xv,
                                                        const int* __restrict__ off,
                                                        const int* __restrict__ csr,
                                                        unsigned* __restrict__ outb, int N) {
    int wid = blockIdx.x * 4 + (threadIdx.x >> 6);
    int lane = threadIdx.x & 63;
    if (wid >= N) return;
    int b0 = off[wid], b1 = off[wid + 1];
    float ax = 0.f, ay = 0.f;
    int i = b0;
    if (BF16IN) {
        const unsigned* X = (const unsigned*)Xv;   // row = 64 uints (128 bf16)
        for (; i + 7 < b1; i += 8) {
            int s0 = csr[i],     s1 = csr[i + 1], s2 = csr[i + 2], s3 = csr[i + 3];
            int s4 = csr[i + 4], s5 = csr[i + 5], s6 = csr[i + 6], s7 = csr[i + 7];
            unsigned v0 = X[(long long)s0 * 64 + lane];
            unsigned v1 = X[(long long)s1 * 64 + lane];
            unsigned v2 = X[(long long)s2 * 64 + lane];
            unsigned v3 = X[(long long)s3 * 64 + lane];
            unsigned v4 = X[(long long)s4 * 64 + lane];
            unsigned v5 = X[(long long)s5 * 64 + lane];
            unsigned v6 = X[(long long)s6 * 64 + lane];
            unsigned v7 = X[(long long)s7 * 64 + lane];
            ax += (blo(v0) + blo(v1)) + (blo(v2) + blo(v3)) +
                  ((blo(v4) + blo(v5)) + (blo(v6) + blo(v7)));
            ay += (bhi(v0) + bhi(v1)) + (bhi(v2) + bhi(v3)) +
                  ((bhi(v4) + bhi(v5)) + (bhi(v6) + bhi(v7)));
        }
        for (; i + 3 < b1; i += 4) {
            int s0 = csr[i], s1 = csr[i + 1], s2 = csr[i + 2], s3 = csr[i + 3];
            unsigned v0 = X[(long long)s0 * 64 + lane];
            unsigned v1 = X[(long long)s1 * 64 + lane];
            unsigned v2 = X[(long long)s2 * 64 + lane];
            unsigned v3 = X[(long long)s3 * 64 + lane];
            ax += blo(v0) + blo(v1) + blo(v2) + blo(v3);
            ay += bhi(v0) + bhi(v1) + bhi(v2) + bhi(v3);
        }
        for (; i < b1; ++i) {
            unsigned v = X[(long long)csr[i] * 64 + lane];
            ax += blo(v); ay += bhi(v);
        }
    } else {
        const float2* X = (const float2*)Xv;
        for (; i + 3 < b1; i += 4) {
            int s0 = csr[i], s1 = csr[i + 1], s2 = csr[i + 2], s3 = csr[i + 3];
            float2 v0 = X[(long long)s0 * 64 + lane];
            float2 v1 = X[(long long)s1 * 64 + lane];
            float2 v2 = X[(long long)s2 * 64 + lane];
            float2 v3 = X[(long long)s3 * 64 + lane];
            ax += v0.x + v1.x + v2.x + v3.x;
            ay += v0.y + v1.y + v2.y + v3.y;
        }
        for (; i < b1; ++i) {
            float2 v = X[(long long)csr[i] * 64 + lane];
            ax += v.x; ay += v.y;
        }
    }
    int dgr = b1 - b0;
    float inv = (dgr > 0) ? 1.0f / (float)dgr : 0.0f;
    unsigned pack = (unsigned)f2b(ax * inv) | ((unsigned)f2b(ay * inv) << 16);
    outb[(long long)wid * 64 + lane] = pack;
}

// ---- MFMA GEMM: Out[r][c] = bias[c] + Am[r]@W[0:128] + Ax[r]@W[128:256] ---
// 512 threads = 8 waves; wave wv owns 16 cols (c0=wv*16), 64 rows (4 frags).
#define WT_SZ   (128 * 264)          // shorts
#define APANEL  (64 * 136)           // shorts
#define ABUF    (2 * APANEL)
#define GEMM_LDS ((WT_SZ + 2 * ABUF) * 2)   // bytes = 137216

template<int XF32, int OUTMODE>
__global__ __launch_bounds__(512, 1) void gemm_mfma_kernel(
    const unsigned short* __restrict__ Am, const void* __restrict__ Ax,
    const float* __restrict__ Wl, const float* __restrict__ Wr,
    const float* __restrict__ bias, void* __restrict__ Out,
    int N, int ntiles)
{
    extern __shared__ unsigned short lds[];
    unsigned short* Wt = lds;
    int t = threadIdx.x;
    int lane = t & 63, wv = t >> 6;
    int lm = lane & 15, q = lane >> 4;
    int c0 = wv * 16;

    // stage Wt[n][k] = (k<128 ? Wl : Wr)[k%128][n], bf16, padded stride 264
    for (int it = 0; it < 32; ++it) {
        int n = t & 127;
        int kp = it * 4 + (t >> 7);           // 0..127
        int k = 2 * kp;
        const float* Wsrc = (k < 128) ? (Wl + k * 128) : (Wr + (k - 128) * 128);
        unsigned pack = (unsigned)f2b(Wsrc[n]) | ((unsigned)f2b(Wsrc[128 + n]) << 16);
        *(unsigned*)(Wt + n * 264 + k) = pack;
    }

    float bias0 = bias[c0 + lm];

    // tile = 64 rows x 16 chunks(short8) per panel = 1024 chunks; 512 thr x j=0..1
    short8 pm[2], px[2];
    auto prefetch = [&](int tl) {
        long long row0 = (long long)tl * 64;
        #pragma unroll
        for (int j = 0; j < 2; ++j) {
            int cid = j * 512 + t;
            int row = cid >> 4, cp = cid & 15;
            long long gr = row0 + row;
            bool ok = gr < (long long)N;
            pm[j] = ok ? *(const short8*)(Am + gr * 128 + cp * 8) : (short8)0;
            if (XF32) {
                short8 s = (short8)0;
                if (ok) {
                    const float* xp = (const float*)Ax + gr * 128 + cp * 8;
                    floatx4 u0 = *(const floatx4*)xp;
                    floatx4 u1 = *(const floatx4*)(xp + 4);
                    s[0] = (short)f2b(u0[0]); s[1] = (short)f2b(u0[1]);
                    s[2] = (short)f2b(u0[2]); s[3] = (short)f2b(u0[3]);
                    s[4] = (short)f2b(u1[0]); s[5] = (short)f2b(u1[1]);
                    s[6] = (short)f2b(u1[2]); s[7] = (short)f2b(u1[3]);
                }
                px[j] = s;
            } else {
                px[j] = ok ? *(const short8*)((const unsigned short*)Ax + gr * 128 + cp * 8)
                           : (short8)0;
            }
        }
    };

    int tile = blockIdx.x;
    if (tile < ntiles) prefetch(tile);
    int buf = 0;
    for (; tile < ntiles; tile += gridDim.x) {
        unsigned short* A = lds + WT_SZ + buf * ABUF;
        __syncthreads();
        #pragma unroll
        for (int j = 0; j < 2; ++j) {
            int cid = j * 512 + t;
            int row = cid >> 4, cp = cid & 15;
            *(short8*)(A + row * 136 + cp * 8) = pm[j];
            *(short8*)(A + APANEL + row * 136 + cp * 8) = px[j];
        }
        __syncthreads();
        int nt = tile + gridDim.x;
        if (nt < ntiles) prefetch(nt);

        floatx4 acc[4];
        #pragma unroll
        for (int rf = 0; rf < 4; ++rf) acc[rf] = (floatx4)bias0;
        #pragma unroll
        for (int ks = 0; ks < 8; ++ks) {
            const unsigned short* P = A + (ks >= 4 ? APANEL : 0);
            int k0 = (ks & 3) * 32 + q * 8;
            short8 b0 = *(const short8*)(Wt + (c0 + lm) * 264 + ks * 32 + q * 8);
            #pragma unroll
            for (int rf = 0; rf < 4; ++rf) {
                short8 a = *(const short8*)(P + (rf * 16 + lm) * 136 + k0);
                acc[rf] = __builtin_amdgcn_mfma_f32_16x16x32_bf16(a, b0, acc[rf], 0, 0, 0);
            }
        }

        long long r0 = (long long)tile * 64;
        int col = c0 + lm;
        #pragma unroll
        for (int rf = 0; rf < 4; ++rf) {
            #pragma unroll
            for (int rg = 0; rg < 4; ++rg) {
                long long rr = r0 + rf * 16 + q * 4 + rg;
                if (rr < (long long)N) {
                    float v = acc[rf][rg];
                    if (OUTMODE != 2) v = fmaxf(v, 0.f);
                    if (OUTMODE == 1)
                        ((unsigned short*)Out)[rr * 128 + col] = f2b(v);
                    else
                        ((float*)Out)[rr * 128 + col] = v;
                }
            }
        }
        buf ^= 1;
    }
}

// ---------------------------------------------------------------------------
extern "C" void kernel_launch(void* const* d_in, const int* in_sizes, int n_in,
                              void* d_out, int out_size, void* d_ws, size_t ws_size,
                              hipStream_t stream) {
    const float* x   = (const float*)d_in[0];
    const int*   eix = (const int*)d_in[1];
    const float* W1l = (const float*)d_in[2];
    const float* b1  = (const float*)d_in[3];
    const float* W1r = (const float*)d_in[4];
    const float* W2l = (const float*)d_in[5];
    const float* b2  = (const float*)d_in[6];
    const float* W2r = (const float*)d_in[7];
    float* out = (float*)d_out;

    int N = in_sizes[0] / 128;
    int E = in_sizes[1] / 2;
    if (N <= 0 || E <= 0) return;
    int nb1 = (N + (1 << BSH1) - 1) >> BSH1;

    char* ws = (char*)d_ws;
    size_t o = 0;
    auto alloc = [&](size_t bytes) -> void* {
        o = (o + 255) & ~(size_t)255;
        void* p = ws + o;
        o += bytes;
        return p;
    };
    int*            flag   = (int*)alloc(4);
    int*            bcnt   = (int*)alloc((size_t)nb1 * 4);
    int*            boff   = (int*)alloc(((size_t)nb1 + 1) * 4);
    int*            bcur   = (int*)alloc((size_t)nb1 * 4);
    int*            off    = (int*)alloc(((size_t)N + 1) * 4);
    int*            csr    = (int*)alloc((size_t)E * 4);
    unsigned short* xb     = (unsigned short*)alloc((size_t)N * 128 * 2);
    unsigned short* meanb  = (unsigned short*)alloc((size_t)N * 128 * 2);
    unsigned short* hb     = (unsigned short*)alloc((size_t)N * 128 * 2);
    bool full = (o <= ws_size);   // room for bf16 h?
    // pairs aliases meanb: dead before spmm writes meanb (needs E*4 <= N*256B)
    unsigned* pairs = (unsigned*)meanb;

    (void)hipFuncSetAttribute((const void*)gemm_mfma_kernel<0, 0>,
                              hipFuncAttributeMaxDynamicSharedMemorySize, GEMM_LDS);
    (void)hipFuncSetAttribute((const void*)gemm_mfma_kernel<0, 1>,
                              hipFuncAttributeMaxDynamicSharedMemorySize, GEMM_LDS);
    (void)hipFuncSetAttribute((const void*)gemm_mfma_kernel<0, 2>,
                              hipFuncAttributeMaxDynamicSharedMemorySize, GEMM_LDS);
    (void)hipFuncSetAttribute((const void*)gemm_mfma_kernel<1, 2>,
                              hipFuncAttributeMaxDynamicSharedMemorySize, GEMM_LDS);

    hipMemsetAsync(bcnt, 0, (size_t)nb1 * 4, stream);

    // CSR build: coarse count -> scan -> chunk-private scatter -> fine sort
    detect_kernel<<<1, 256, 0, stream>>>(eix, in_sizes[1], flag);
    size_t cnt_lds = (size_t)nb1 * 4;
    coarse_count_kernel<<<256, 256, cnt_lds, stream>>>(eix, flag, bcnt, E, nb1);
    scan_kernel<<<1, 1024, 0, stream>>>(bcnt, boff, bcur, nb1);
    int nchunks = (E + CHUNK - 1) / CHUNK;
    int sgrid = nchunks < 2048 ? nchunks : 2048;
    coarse_scatter_kernel<<<sgrid, 256, 2 * cnt_lds, stream>>>(eix, flag, bcur, pairs, E, nb1);
    fine_csr_kernel<<<nb1, 256, 0, stream>>>(pairs, boff, off, csr, N, nb1, E);

    // x -> bf16
    cvt_kernel<<<2048, 256, 0, stream>>>(x, xb, N * 32);

    int spmm_grid = (N + 3) / 4;
    int ntiles = (N + 63) / 64;
    int ggrid = ntiles < 256 ? ntiles : 256;

    // layer 1
    spmm_mean_kernel<1><<<spmm_grid, 256, 0, stream>>>(xb, off, csr, (unsigned*)meanb, N);
    if (full) {
        gemm_mfma_kernel<0, 1><<<ggrid, 512, GEMM_LDS, stream>>>(
            meanb, xb, W1l, W1r, b1, hb, N, ntiles);
        spmm_mean_kernel<1><<<spmm_grid, 256, 0, stream>>>(hb, off, csr, (unsigned*)meanb, N);
        gemm_mfma_kernel<0, 2><<<ggrid, 512, GEMM_LDS, stream>>>(
            meanb, hb, W2l, W2r, b2, out, N, ntiles);
    } else {
        gemm_mfma_kernel<0, 0><<<ggrid, 512, GEMM_LDS, stream>>>(
            meanb, xb, W1l, W1r, b1, out, N, ntiles);
        spmm_mean_kernel<0><<<spmm_grid, 256, 0, stream>>>(out, off, csr, (unsigned*)meanb, N);
        gemm_mfma_kernel<1, 2><<<ggrid, 512, GEMM_LDS, stream>>>(
            meanb, out, W2l, W2r, b2, out, N, ntiles);
    }
}